// Round 5
// baseline (241.961 us; speedup 1.0000x reference)
//
#include <hip/hip_runtime.h>
#include <stdint.h>

typedef __bf16 bf16;
typedef __bf16 bf16x8 __attribute__((ext_vector_type(8)));
typedef float  f32x4  __attribute__((ext_vector_type(4)));
typedef unsigned short u16x4 __attribute__((ext_vector_type(4)));
typedef unsigned int   u32x4v __attribute__((ext_vector_type(4)));

#define SEQ   2048
#define DM    768
#define NH    12
#define HD    64
#define ATT_SCALE 0.125f
#define LOG2E 1.44269504f
#define LN_EPS 1e-5f

// async global->LDS, 16B per lane; LDS dest is wave-uniform base + lane*16
__device__ __forceinline__ void gload16(const void* g, void* l) {
  __builtin_amdgcn_global_load_lds((const __attribute__((address_space(1))) void*)g,
                                   (__attribute__((address_space(3))) void*)l,
                                   16, 0, 0);
}

// ---------------- prep: transpose fp32 768x768 weights -> bf16 col-major ----
__global__ __launch_bounds__(256) void transpose_w(
    const float* __restrict__ Wq, const float* __restrict__ Wk,
    const float* __restrict__ Wv, const float* __restrict__ Wo,
    bf16* __restrict__ Wqkvt, bf16* __restrict__ Wot)
{
  __shared__ float tile[32][33];
  int z = blockIdx.z;
  const float* src = (z==0)?Wq:(z==1)?Wk:(z==2)?Wv:Wo;
  int r0 = blockIdx.y*32, c0 = blockIdx.x*32;
  int tx = threadIdx.x, ty = threadIdx.y; // (32,8)
  #pragma unroll
  for (int i=ty;i<32;i+=8) tile[i][tx] = src[(size_t)(r0+i)*DM + c0+tx];
  __syncthreads();
  bf16* dst = (z<3) ? (Wqkvt + (size_t)z*DM*DM) : Wot;
  #pragma unroll
  for (int i=ty;i<32;i+=8) dst[(size_t)(c0+i)*DM + r0+tx] = (bf16)tile[tx][i];
}

// ---------------- LayerNorm: one row (768 fp32) per block -> bf16 -----------
__global__ __launch_bounds__(256) void ln_kernel(
    const float* __restrict__ x, const float* __restrict__ gamma,
    const float* __restrict__ beta, bf16* __restrict__ h)
{
  int row = blockIdx.x;
  const float* xr = x + (size_t)row*DM;
  int t = threadIdx.x;
  float v0 = xr[t], v1 = xr[t+256], v2 = xr[t+512];
  float s = v0+v1+v2;
  float q = v0*v0+v1*v1+v2*v2;
  #pragma unroll
  for (int m=32;m>=1;m>>=1){ s += __shfl_xor(s,m,64); q += __shfl_xor(q,m,64); }
  __shared__ float rs[4], rq[4];
  int w = t>>6;
  if ((t&63)==0){ rs[w]=s; rq[w]=q; }
  __syncthreads();
  float S = rs[0]+rs[1]+rs[2]+rs[3];
  float Q = rq[0]+rq[1]+rq[2]+rq[3];
  float mean = S*(1.0f/DM);
  float var  = Q*(1.0f/DM) - mean*mean;
  float rstd = rsqrtf(var + LN_EPS);
  bf16* hr = h + (size_t)row*DM;
  hr[t]     = (bf16)((v0-mean)*rstd*gamma[t]     + beta[t]);
  hr[t+256] = (bf16)((v1-mean)*rstd*gamma[t+256] + beta[t+256]);
  hr[t+512] = (bf16)((v2-mean)*rstd*gamma[t+512] + beta[t+512]);
}

// ---------------- GEMM: C[M][N] = A[M][K] * B, with B given as Bt[N][K] -----
// EPI 0: QKV epilogue. Q cols (<768) scaled by LOG2E (attn uses exp2 directly).
//        cols<1536 -> qk bf16 [4096][1536]; cols>=1536 -> V^T [b][h][d][n]
// EPI 1: out fp32 = acc + bo[col] + x[row][col]
template<int BM, int BN, int WM, int WN, int EPI>
__global__ __launch_bounds__(256) void gemm_bt(
    const bf16* __restrict__ A, const bf16* __restrict__ Bt, int K,
    bf16* __restrict__ qk, bf16* __restrict__ vt,
    float* __restrict__ out, const float* __restrict__ bo, const float* __restrict__ xres)
{
  constexpr int MF = BM/(WM*16);
  constexpr int NF = BN/(WN*16);
  __shared__ bf16 As[BM][64];
  __shared__ bf16 Bs[BN][64];
  int tid = threadIdx.x, w = tid>>6, la = tid&63;
  int bn = blockIdx.x, bm = blockIdx.y;
  int wm = w / WN, wn = w % WN;
  int g = la>>4, li = la&15;
  int lr = la>>3, lc = (la&7)*8;
  f32x4 acc[MF][NF] = {};

  for (int kt=0; kt<K/64; ++kt) {
    int k0 = kt*64;
    #pragma unroll
    for (int i=0;i<BM/32;i++){ int c=i*4+w;
      gload16(A + ((size_t)(bm*BM + c*8 + lr))*K + k0 + lc, &As[c*8][0]); }
    #pragma unroll
    for (int i=0;i<BN/32;i++){ int c=i*4+w;
      gload16(Bt + ((size_t)(bn*BN + c*8 + lr))*K + k0 + lc, &Bs[c*8][0]); }
    __syncthreads();
    #pragma unroll
    for (int kk=0;kk<2;kk++){
      bf16x8 af[MF], bfr[NF];
      #pragma unroll
      for (int i=0;i<MF;i++) af[i]  = *(const bf16x8*)&As[wm*(BM/WM)+i*16+li][kk*32+g*8];
      #pragma unroll
      for (int j=0;j<NF;j++) bfr[j] = *(const bf16x8*)&Bs[wn*(BN/WN)+j*16+li][kk*32+g*8];
      #pragma unroll
      for (int i=0;i<MF;i++)
        #pragma unroll
        for (int j=0;j<NF;j++)
          acc[i][j] = __builtin_amdgcn_mfma_f32_16x16x32_bf16(af[i], bfr[j], acc[i][j], 0,0,0);
    }
    __syncthreads();
  }

  #pragma unroll
  for (int i=0;i<MF;i++){
    int row0 = bm*BM + wm*(BM/WM) + i*16 + g*4;
    #pragma unroll
    for (int j=0;j<NF;j++){
      int col = bn*BN + wn*(BN/WN) + j*16 + li;
      if (EPI==0){
        if (col < 1536) {
          float qs = (col < 768) ? LOG2E : 1.0f;   // uniform per j-tile (768%BN==0)
          #pragma unroll
          for (int r=0;r<4;r++) qk[(size_t)(row0+r)*1536 + col] = (bf16)(acc[i][j][r]*qs);
        } else {
          int cv = col - 1536; int hh = cv>>6, dd = cv&63;
          int b_ = row0>>11,  n0 = row0&2047;
          u16x4 u;
          #pragma unroll
          for (int r=0;r<4;r++){ bf16 bv = (bf16)acc[i][j][r];
            u[r] = __builtin_bit_cast(unsigned short, bv); }
          *reinterpret_cast<u16x4*>(vt + ((size_t)((b_*NH+hh)*HD+dd))*SEQ + n0) = u;
        }
      } else {
        float bb = bo[col];
        #pragma unroll
        for (int r=0;r<4;r++){ size_t idx = (size_t)(row0+r)*DM + col;
          out[idx] = acc[i][j][r] + bb + xres[idx]; }
      }
    }
  }
}

// ---------------- flash attention: no LDS, no barriers, swapped QK ----------
// Grid: 768 linear blocks; id&7 pins an XCD, each XCD owns 3 (b,h) pairs so
// its private L2 holds that K/V working set (~1.5 MB < 4 MB).
// Per wave: 16 q-rows (q = li), K/V frags loaded global->VGPR (L2-hit),
// compiler emits counted vmcnt waits; no block-wide sync anywhere.
// Swapped QK: s[nf][r] = S[kv=nf*16+g*4+r][q=li]; softmax is shuffle-free.
// P -> PV B-operand via in-register exchange: cvt_pk + permlane32/16_swap
// (3-cycle bit permutation reg-bit<-b4<-b5<-reg-bit as two transposes).
__global__ __launch_bounds__(256) void attn_kernel(
    const bf16* __restrict__ QK, const bf16* __restrict__ Vt, bf16* __restrict__ vals)
{
  int tid=threadIdx.x, w=tid>>6, la=tid&63;
  int id = blockIdx.x;
  int xcd = id & 7, idx = id >> 3;       // 768 = 8 * 96, bijective
  int bh  = xcd*3 + (idx>>5);            // 0..23
  int qt  = idx & 31;
  int b = bh/NH, hh = bh%NH;
  int g=la>>4, li=la&15;
  size_t qrow0=(size_t)b*SEQ + qt*64;

  // Q frags (B-operand): Q[q=li][k], pre-scaled by LOG2E in GEMM1
  bf16x8 qf[2];
  {
    const bf16* qp = QK + (qrow0 + w*16 + li)*1536 + hh*64;
    qf[0] = *(const bf16x8*)(qp + g*8);
    qf[1] = *(const bf16x8*)(qp + 32 + g*8);
  }

  const bf16* Kb = QK + (size_t)b*SEQ*1536 + 768 + hh*64;
  const bf16* Vb = Vt + (size_t)(b*NH+hh)*HD*SEQ;
  const bf16* Krow[4]; const bf16* Vrow[4];
  #pragma unroll
  for (int nf=0;nf<4;nf++) Krow[nf] = Kb + (size_t)(nf*16+li)*1536 + g*8;
  #pragma unroll
  for (int df=0;df<4;df++) Vrow[df] = Vb + (size_t)(df*16+li)*SEQ + g*8;

  f32x4 o[4] = {};
  float lpart = 0.f;

  for (int t=0;t<32;t++){
    size_t j0 = (size_t)t*64;
    // K frags (A-operand: K[kv=nf*16+li][k=kk*32+g*8..+7]) — needed first
    bf16x8 kf[2][4];
    #pragma unroll
    for (int nf=0;nf<4;nf++){
      kf[0][nf] = *(const bf16x8*)(Krow[nf] + j0*1536);
      kf[1][nf] = *(const bf16x8*)(Krow[nf] + j0*1536 + 32);
    }
    // V frags (A-operand: V^T[d=df*16+li][kv=j0+ks*32+g*8..]) — used after softmax
    bf16x8 vb[2][4];
    #pragma unroll
    for (int df=0;df<4;df++){
      vb[0][df] = *(const bf16x8*)(Vrow[df] + j0);
      vb[1][df] = *(const bf16x8*)(Vrow[df] + j0 + 32);
    }
    // S = K Q^T (swapped): D[kv][q]
    f32x4 s[4] = {};
    __builtin_amdgcn_s_setprio(1);
    #pragma unroll
    for (int kk=0;kk<2;kk++)
      #pragma unroll
      for (int nf=0;nf<4;nf++)
        s[nf] = __builtin_amdgcn_mfma_f32_16x16x32_bf16(kf[kk][nf], qf[kk], s[nf], 0,0,0);
    __builtin_amdgcn_s_setprio(0);
    // static-max softmax: p = 2^s (lane-local row; no shuffles)
    float p[4][4];
    #pragma unroll
    for (int nf=0;nf<4;nf++)
      #pragma unroll
      for (int r=0;r<4;r++){
        p[nf][r] = __builtin_amdgcn_exp2f(s[nf][r]);
        lpart += p[nf][r];
      }
    // exchange: per 32-kv half, build PV B-frag pa[ks] in registers
    bf16x8 pa[2];
    #pragma unroll
    for (int ks=0;ks<2;ks++){
      unsigned int c00,c01,c10,c11;
      asm("v_cvt_pk_bf16_f32 %0, %1, %2" : "=v"(c00) : "v"(p[2*ks  ][0]), "v"(p[2*ks  ][1]));
      asm("v_cvt_pk_bf16_f32 %0, %1, %2" : "=v"(c01) : "v"(p[2*ks  ][2]), "v"(p[2*ks  ][3]));
      asm("v_cvt_pk_bf16_f32 %0, %1, %2" : "=v"(c10) : "v"(p[2*ks+1][0]), "v"(p[2*ks+1][1]));
      asm("v_cvt_pk_bf16_f32 %0, %1, %2" : "=v"(c11) : "v"(p[2*ks+1][2]), "v"(p[2*ks+1][3]));
      // T1: transpose reg-bit (nf parity) <-> lane bit5
      asm("v_permlane32_swap_b32 %0, %1" : "+v"(c10), "+v"(c00));
      asm("v_permlane32_swap_b32 %0, %1" : "+v"(c11), "+v"(c01));
      // T2: transpose reg-bit <-> lane bit4
      asm("v_permlane16_swap_b32 %0, %1" : "+v"(c10), "+v"(c00));
      asm("v_permlane16_swap_b32 %0, %1" : "+v"(c11), "+v"(c01));
      u32x4v cc = {c00, c01, c10, c11};
      pa[ks] = __builtin_bit_cast(bf16x8, cc);
    }
    // PV: O[d][q] += V^T[d][kv] * P[kv][q]
    __builtin_amdgcn_s_setprio(1);
    #pragma unroll
    for (int ks=0;ks<2;ks++)
      #pragma unroll
      for (int df=0;df<4;df++)
        o[df] = __builtin_amdgcn_mfma_f32_16x16x32_bf16(vb[ks][df], pa[ks], o[df], 0,0,0);
    __builtin_amdgcn_s_setprio(0);
  }
  // l over g-lane quarters (q-row li), then epilogue: O * SCALE / l
  float lsum = lpart;
  lsum += __shfl_xor(lsum, 16, 64);
  lsum += __shfl_xor(lsum, 32, 64);
  float fac = ATT_SCALE / lsum;
  bf16* vrow = vals + (qrow0 + w*16 + li)*DM + hh*64;
  #pragma unroll
  for (int df=0;df<4;df++){
    u16x4 u;
    #pragma unroll
    for (int r=0;r<4;r++){
      bf16 bv = (bf16)(o[df][r] * fac);
      u[r] = __builtin_bit_cast(unsigned short, bv);
    }
    *reinterpret_cast<u16x4*>(vrow + df*16 + g*4) = u;
  }
}

// ---------------- launch -----------------------------------------------------
extern "C" void kernel_launch(void* const* d_in, const int* in_sizes, int n_in,
                              void* d_out, int out_size, void* d_ws, size_t ws_size,
                              hipStream_t stream)
{
  const float* x     = (const float*)d_in[0];
  const float* Wq    = (const float*)d_in[1];
  const float* Wk    = (const float*)d_in[2];
  const float* Wv    = (const float*)d_in[3];
  const float* Wo    = (const float*)d_in[4];
  const float* bo    = (const float*)d_in[5];
  const float* gamma = (const float*)d_in[6];
  const float* beta  = (const float*)d_in[7];
  float* out = (float*)d_out;
  char* ws = (char*)d_ws;

  bf16* h     = (bf16*)(ws + 0);          // 4096*768*2    = 6291456
  bf16* vals  = (bf16*)(ws + 0);          // alias of h (h dead after GEMM1)
  bf16* Wqkvt = (bf16*)(ws + 6291456);    // 2304*768*2    = 3538944
  bf16* Wot   = (bf16*)(ws + 9830400);    // 768*768*2     = 1179648
  bf16* QKb   = (bf16*)(ws + 11010048);   // 4096*1536*2   = 12582912
  bf16* Vt    = (bf16*)(ws + 23592960);   // 24*64*2048*2  = 6291456
  (void)ws_size; (void)in_sizes; (void)n_in; (void)out_size;

  transpose_w<<<dim3(24,24,4), dim3(32,8), 0, stream>>>(Wq,Wk,Wv,Wo, Wqkvt, Wot);
  ln_kernel<<<dim3(4096), dim3(256), 0, stream>>>(x, gamma, beta, h);
  gemm_bt<128,128,2,2,0><<<dim3(18,32), dim3(256), 0, stream>>>(
      h, Wqkvt, DM, QKb, Vt, nullptr, nullptr, nullptr);
  attn_kernel<<<dim3(768), dim3(256), 0, stream>>>(QKb, Vt, vals);
  gemm_bt<64,64,2,2,1><<<dim3(12,64), dim3(256), 0, stream>>>(
      vals, Wot, DM, nullptr, nullptr, out, bo, x);
}

// Round 6
// 117.835 us; speedup vs baseline: 2.0534x; 2.0534x over previous
//
#include <hip/hip_runtime.h>
#include <stdint.h>

typedef __bf16 bf16;
typedef __bf16 bf16x8 __attribute__((ext_vector_type(8)));
typedef float  f32x4  __attribute__((ext_vector_type(4)));
typedef unsigned short u16x4 __attribute__((ext_vector_type(4)));
typedef unsigned int   u32x4v __attribute__((ext_vector_type(4)));

#define SEQ   2048
#define DM    768
#define NH    12
#define HD    64
#define ATT_SCALE 0.125f
#define LOG2E 1.44269504f
#define LN_EPS 1e-5f

// async global->LDS, 16B per lane; LDS dest is wave-uniform base + lane*16
__device__ __forceinline__ void gload16(const void* g, void* l) {
  __builtin_amdgcn_global_load_lds((const __attribute__((address_space(1))) void*)g,
                                   (__attribute__((address_space(3))) void*)l,
                                   16, 0, 0);
}

// ---------------- prep: transpose fp32 768x768 weights -> bf16 col-major ----
__global__ __launch_bounds__(256) void transpose_w(
    const float* __restrict__ Wq, const float* __restrict__ Wk,
    const float* __restrict__ Wv, const float* __restrict__ Wo,
    bf16* __restrict__ Wqkvt, bf16* __restrict__ Wot)
{
  __shared__ float tile[32][33];
  int z = blockIdx.z;
  const float* src = (z==0)?Wq:(z==1)?Wk:(z==2)?Wv:Wo;
  int r0 = blockIdx.y*32, c0 = blockIdx.x*32;
  int tx = threadIdx.x, ty = threadIdx.y; // (32,8)
  #pragma unroll
  for (int i=ty;i<32;i+=8) tile[i][tx] = src[(size_t)(r0+i)*DM + c0+tx];
  __syncthreads();
  bf16* dst = (z<3) ? (Wqkvt + (size_t)z*DM*DM) : Wot;
  #pragma unroll
  for (int i=ty;i<32;i+=8) dst[(size_t)(c0+i)*DM + r0+tx] = (bf16)tile[tx][i];
}

// ---------------- LayerNorm: one row (768 fp32) per block -> bf16 -----------
__global__ __launch_bounds__(256) void ln_kernel(
    const float* __restrict__ x, const float* __restrict__ gamma,
    const float* __restrict__ beta, bf16* __restrict__ h)
{
  int row = blockIdx.x;
  const float* xr = x + (size_t)row*DM;
  int t = threadIdx.x;
  float v0 = xr[t], v1 = xr[t+256], v2 = xr[t+512];
  float s = v0+v1+v2;
  float q = v0*v0+v1*v1+v2*v2;
  #pragma unroll
  for (int m=32;m>=1;m>>=1){ s += __shfl_xor(s,m,64); q += __shfl_xor(q,m,64); }
  __shared__ float rs[4], rq[4];
  int w = t>>6;
  if ((t&63)==0){ rs[w]=s; rq[w]=q; }
  __syncthreads();
  float S = rs[0]+rs[1]+rs[2]+rs[3];
  float Q = rq[0]+rq[1]+rq[2]+rq[3];
  float mean = S*(1.0f/DM);
  float var  = Q*(1.0f/DM) - mean*mean;
  float rstd = rsqrtf(var + LN_EPS);
  bf16* hr = h + (size_t)row*DM;
  hr[t]     = (bf16)((v0-mean)*rstd*gamma[t]     + beta[t]);
  hr[t+256] = (bf16)((v1-mean)*rstd*gamma[t+256] + beta[t+256]);
  hr[t+512] = (bf16)((v2-mean)*rstd*gamma[t+512] + beta[t+512]);
}

// ---------------- GEMM: C[M][N] = A[M][K] * B, with B given as Bt[N][K] -----
// EPI 0: QKV epilogue. Q cols (<768) scaled by LOG2E (attn uses exp2 directly).
//        cols<1536 -> qk bf16 [4096][1536]; cols>=1536 -> V^T [b][h][d][n]
// EPI 1: out fp32 = acc + bo[col] + x[row][col]
template<int BM, int BN, int WM, int WN, int EPI>
__global__ __launch_bounds__(256) void gemm_bt(
    const bf16* __restrict__ A, const bf16* __restrict__ Bt, int K,
    bf16* __restrict__ qk, bf16* __restrict__ vt,
    float* __restrict__ out, const float* __restrict__ bo, const float* __restrict__ xres)
{
  constexpr int MF = BM/(WM*16);
  constexpr int NF = BN/(WN*16);
  __shared__ bf16 As[BM][64];
  __shared__ bf16 Bs[BN][64];
  int tid = threadIdx.x, w = tid>>6, la = tid&63;
  int bn = blockIdx.x, bm = blockIdx.y;
  int wm = w / WN, wn = w % WN;
  int g = la>>4, li = la&15;
  int lr = la>>3, lc = (la&7)*8;
  f32x4 acc[MF][NF] = {};

  for (int kt=0; kt<K/64; ++kt) {
    int k0 = kt*64;
    #pragma unroll
    for (int i=0;i<BM/32;i++){ int c=i*4+w;
      gload16(A + ((size_t)(bm*BM + c*8 + lr))*K + k0 + lc, &As[c*8][0]); }
    #pragma unroll
    for (int i=0;i<BN/32;i++){ int c=i*4+w;
      gload16(Bt + ((size_t)(bn*BN + c*8 + lr))*K + k0 + lc, &Bs[c*8][0]); }
    __syncthreads();
    #pragma unroll
    for (int kk=0;kk<2;kk++){
      bf16x8 af[MF], bfr[NF];
      #pragma unroll
      for (int i=0;i<MF;i++) af[i]  = *(const bf16x8*)&As[wm*(BM/WM)+i*16+li][kk*32+g*8];
      #pragma unroll
      for (int j=0;j<NF;j++) bfr[j] = *(const bf16x8*)&Bs[wn*(BN/WN)+j*16+li][kk*32+g*8];
      #pragma unroll
      for (int i=0;i<MF;i++)
        #pragma unroll
        for (int j=0;j<NF;j++)
          acc[i][j] = __builtin_amdgcn_mfma_f32_16x16x32_bf16(af[i], bfr[j], acc[i][j], 0,0,0);
    }
    __syncthreads();
  }

  #pragma unroll
  for (int i=0;i<MF;i++){
    int row0 = bm*BM + wm*(BM/WM) + i*16 + g*4;
    #pragma unroll
    for (int j=0;j<NF;j++){
      int col = bn*BN + wn*(BN/WN) + j*16 + li;
      if (EPI==0){
        if (col < 1536) {
          float qs = (col < 768) ? LOG2E : 1.0f;   // uniform per j-tile (768%BN==0)
          #pragma unroll
          for (int r=0;r<4;r++) qk[(size_t)(row0+r)*1536 + col] = (bf16)(acc[i][j][r]*qs);
        } else {
          int cv = col - 1536; int hh = cv>>6, dd = cv&63;
          int b_ = row0>>11,  n0 = row0&2047;
          u16x4 u;
          #pragma unroll
          for (int r=0;r<4;r++){ bf16 bv = (bf16)acc[i][j][r];
            u[r] = __builtin_bit_cast(unsigned short, bv); }
          *reinterpret_cast<u16x4*>(vt + ((size_t)((b_*NH+hh)*HD+dd))*SEQ + n0) = u;
        }
      } else {
        float bb = bo[col];
        #pragma unroll
        for (int r=0;r<4;r++){ size_t idx = (size_t)(row0+r)*DM + col;
          out[idx] = acc[i][j][r] + bb + xres[idx]; }
      }
    }
  }
}

// ---------------- flash attention: LDS-staged K/V + swapped QK + in-reg P ---
// block = (qt, h, b): 64 Q rows, 4 waves x 16 rows. KV tiles of 64, dbuf LDS,
// XOR-swizzle (slot ^= row&7) staged via pre-swizzled global src. One barrier
// per iter; prefetch issued right after it, drained by next iter's barrier.
// Swapped QK: s[nf] = mfma(K, Q) -> S[kv=nf*16+g*4+r][q=li] lane-local per
// q-row: softmax is shuffle-free, P never touches LDS. P->PV-B-operand is a
// pure register bit-permutation: need (reg-hi,l5,l4):(x,y,z)->(z,x,y), which
// is P32-transpose(reg,l5) then P16-transpose(reg,l4), BOTH with the reg0
// word as vdst (VDST<-{lo,lo}, VSRC<-{hi,hi}; vdst=reg1 gives the
// anti-transpose — that was round 5's silent-corruption bug).
__global__ __launch_bounds__(256) void attn_kernel(
    const bf16* __restrict__ QK, const bf16* __restrict__ Vt, bf16* __restrict__ vals)
{
  __shared__ bf16 Ks[2][64][64];
  __shared__ bf16 Vs[2][64][64];   // V^T tile: [d][kv]
  int tid=threadIdx.x, w=tid>>6, la=tid&63;
  int qt=blockIdx.x, hh=blockIdx.y, b=blockIdx.z;
  int g=la>>4, li=la&15;
  int lr=la>>3;
  int lx=li&7;
  int lcs=((la&7)^lr)*8;           // swizzled source column (elements)
  size_t qrow0=(size_t)b*SEQ + qt*64;

  // Q frags (B-operand: Q[q=li][k]), pre-scaled by LOG2E in GEMM1; registers
  bf16x8 qf[2];
  {
    const bf16* qp = QK + (qrow0 + w*16 + li)*1536 + hh*64;
    qf[0] = *(const bf16x8*)(qp + g*8);
    qf[1] = *(const bf16x8*)(qp + 32 + g*8);
  }

  const bf16* Kbase = QK + (size_t)b*SEQ*1536 + 768 + hh*64;
  const bf16* Vbase = Vt + (size_t)(b*NH+hh)*HD*SEQ;
  #pragma unroll
  for (int i=0;i<2;i++){ int c=i*4+w;
    gload16(Kbase + (size_t)(c*8+lr)*1536 + lcs, &Ks[0][c*8][0]);
    gload16(Vbase + (size_t)(c*8+lr)*SEQ  + lcs, &Vs[0][c*8][0]); }
  __syncthreads();

  f32x4 o[4] = {};
  float lp[4] = {0.f,0.f,0.f,0.f};

  for (int t=0;t<32;t++){
    int buf=t&1;
    if (t) __syncthreads();
    if (t+1<32){
      int j0=(t+1)*64;
      #pragma unroll
      for (int i=0;i<2;i++){ int c=i*4+w;
        gload16(Kbase + (size_t)(j0+c*8+lr)*1536 + lcs, &Ks[buf^1][c*8][0]);
        gload16(Vbase + (size_t)(c*8+lr)*SEQ + j0 + lcs, &Vs[buf^1][c*8][0]); }
    }
    // S = K Q^T (swapped): lane holds S[kv=nf*16+g*4+r][q=li]
    f32x4 s[4] = {};
    #pragma unroll
    for (int kk=0;kk<2;kk++){
      bf16x8 kf[4];
      #pragma unroll
      for (int nf=0;nf<4;nf++){
        int row = nf*16+li;
        kf[nf] = *(const bf16x8*)((const char*)&Ks[buf][0][0] + row*128 + (((kk*4+g)^lx)<<4));
      }
      __builtin_amdgcn_s_setprio(1);
      #pragma unroll
      for (int nf=0;nf<4;nf++)
        s[nf] = __builtin_amdgcn_mfma_f32_16x16x32_bf16(kf[nf], qf[kk], s[nf], 0,0,0);
      __builtin_amdgcn_s_setprio(0);
    }
    // static-max softmax: p = 2^s, lane-local; 4 independent partial-sum chains
    float p[4][4];
    #pragma unroll
    for (int nf=0;nf<4;nf++){
      #pragma unroll
      for (int r=0;r<4;r++){
        p[nf][r] = __builtin_amdgcn_exp2f(s[nf][r]);
        lp[nf] += p[nf][r];
      }
    }
    // in-register exchange: build PV B-frags pa[ks] (P[kv][q=li])
    bf16x8 pa[2];
    #pragma unroll
    for (int ks=0;ks<2;ks++){
      unsigned int c00,c01,c10,c11;
      asm("v_cvt_pk_bf16_f32 %0, %1, %2" : "=v"(c00) : "v"(p[2*ks  ][0]), "v"(p[2*ks  ][1]));
      asm("v_cvt_pk_bf16_f32 %0, %1, %2" : "=v"(c01) : "v"(p[2*ks  ][2]), "v"(p[2*ks  ][3]));
      asm("v_cvt_pk_bf16_f32 %0, %1, %2" : "=v"(c10) : "v"(p[2*ks+1][0]), "v"(p[2*ks+1][1]));
      asm("v_cvt_pk_bf16_f32 %0, %1, %2" : "=v"(c11) : "v"(p[2*ks+1][2]), "v"(p[2*ks+1][3]));
      // transpose (reg-bit, lane-b5): vdst MUST be the reg0 word
      asm("v_permlane32_swap_b32 %0, %1" : "+v"(c00), "+v"(c10));
      asm("v_permlane32_swap_b32 %0, %1" : "+v"(c01), "+v"(c11));
      // transpose (reg-bit, lane-b4)
      asm("v_permlane16_swap_b32 %0, %1" : "+v"(c00), "+v"(c10));
      asm("v_permlane16_swap_b32 %0, %1" : "+v"(c01), "+v"(c11));
      u32x4v cc = {c00, c01, c10, c11};
      pa[ks] = __builtin_bit_cast(bf16x8, cc);
    }
    // PV: O[d][q] += V^T[d][kv] * P[kv][q]
    #pragma unroll
    for (int ks=0;ks<2;ks++){
      bf16x8 vb[4];
      #pragma unroll
      for (int df=0;df<4;df++){
        int row = df*16+li;
        vb[df] = *(const bf16x8*)((const char*)&Vs[buf][0][0] + row*128 + (((ks*4+g)^lx)<<4));
      }
      __builtin_amdgcn_s_setprio(1);
      #pragma unroll
      for (int df=0;df<4;df++)
        o[df] = __builtin_amdgcn_mfma_f32_16x16x32_bf16(vb[df], pa[ks], o[df], 0,0,0);
      __builtin_amdgcn_s_setprio(0);
    }
  }
  // lane holds O[d=df*16+g*4+r][q=li]; l-sum over g-quarters; scale AFTER
  // softmax per module semantics => O * SCALE / l
  float lsum = lp[0]+lp[1]+lp[2]+lp[3];
  lsum += __shfl_xor(lsum, 16, 64);
  lsum += __shfl_xor(lsum, 32, 64);
  float fac = ATT_SCALE / lsum;
  bf16* vrow = vals + (qrow0 + w*16 + li)*DM + hh*64;
  #pragma unroll
  for (int df=0;df<4;df++){
    u16x4 u;
    #pragma unroll
    for (int r=0;r<4;r++){
      bf16 bv = (bf16)(o[df][r] * fac);
      u[r] = __builtin_bit_cast(unsigned short, bv);
    }
    *reinterpret_cast<u16x4*>(vrow + df*16 + g*4) = u;
  }
}

// ---------------- launch -----------------------------------------------------
extern "C" void kernel_launch(void* const* d_in, const int* in_sizes, int n_in,
                              void* d_out, int out_size, void* d_ws, size_t ws_size,
                              hipStream_t stream)
{
  const float* x     = (const float*)d_in[0];
  const float* Wq    = (const float*)d_in[1];
  const float* Wk    = (const float*)d_in[2];
  const float* Wv    = (const float*)d_in[3];
  const float* Wo    = (const float*)d_in[4];
  const float* bo    = (const float*)d_in[5];
  const float* gamma = (const float*)d_in[6];
  const float* beta  = (const float*)d_in[7];
  float* out = (float*)d_out;
  char* ws = (char*)d_ws;

  bf16* h     = (bf16*)(ws + 0);          // 4096*768*2    = 6291456
  bf16* vals  = (bf16*)(ws + 0);          // alias of h (h dead after GEMM1)
  bf16* Wqkvt = (bf16*)(ws + 6291456);    // 2304*768*2    = 3538944
  bf16* Wot   = (bf16*)(ws + 9830400);    // 768*768*2     = 1179648
  bf16* QKb   = (bf16*)(ws + 11010048);   // 4096*1536*2   = 12582912
  bf16* Vt    = (bf16*)(ws + 23592960);   // 24*64*2048*2  = 6291456
  (void)ws_size; (void)in_sizes; (void)n_in; (void)out_size;

  transpose_w<<<dim3(24,24,4), dim3(32,8), 0, stream>>>(Wq,Wk,Wv,Wo, Wqkvt, Wot);
  ln_kernel<<<dim3(4096), dim3(256), 0, stream>>>(x, gamma, beta, h);
  gemm_bt<128,128,2,2,0><<<dim3(18,32), dim3(256), 0, stream>>>(
      h, Wqkvt, DM, QKb, Vt, nullptr, nullptr, nullptr);
  attn_kernel<<<dim3(32,12,2), dim3(256), 0, stream>>>(QKb, Vt, vals);
  gemm_bt<64,64,2,2,1><<<dim3(12,64), dim3(256), 0, stream>>>(
      vals, Wot, DM, nullptr, nullptr, out, bo, x);
}

// Round 7
// 103.441 us; speedup vs baseline: 2.3391x; 1.1392x over previous
//
#include <hip/hip_runtime.h>
#include <stdint.h>

typedef __bf16 bf16;
typedef __bf16 bf16x8 __attribute__((ext_vector_type(8)));
typedef float  f32x4  __attribute__((ext_vector_type(4)));
typedef unsigned short u16x4 __attribute__((ext_vector_type(4)));
typedef unsigned int   u32x4v __attribute__((ext_vector_type(4)));

#define SEQ   2048
#define DM    768
#define NH    12
#define HD    64
#define ATT_SCALE 0.125f
#define LOG2E 1.44269504f
#define LN_EPS 1e-5f

// async global->LDS, 16B per lane; LDS dest is wave-uniform base + lane*16
__device__ __forceinline__ void gload16(const void* g, void* l) {
  __builtin_amdgcn_global_load_lds((const __attribute__((address_space(1))) void*)g,
                                   (__attribute__((address_space(3))) void*)l,
                                   16, 0, 0);
}

// ---------------- prep: LN (blocks 0..4095) + weight transpose (4096..6399) -
__global__ __launch_bounds__(256) void prep_kernel(
    const float* __restrict__ x, const float* __restrict__ gamma,
    const float* __restrict__ beta, bf16* __restrict__ h,
    const float* __restrict__ Wq, const float* __restrict__ Wk,
    const float* __restrict__ Wv, const float* __restrict__ Wo,
    bf16* __restrict__ Wqkvt, bf16* __restrict__ Wot)
{
  __shared__ float smem[32*33];
  int bid = blockIdx.x, t = threadIdx.x;
  if (bid < 4096) {
    const float* xr = x + (size_t)bid*DM;
    float v0 = xr[t], v1 = xr[t+256], v2 = xr[t+512];
    float s = v0+v1+v2;
    float q = v0*v0+v1*v1+v2*v2;
    #pragma unroll
    for (int m=32;m>=1;m>>=1){ s += __shfl_xor(s,m,64); q += __shfl_xor(q,m,64); }
    float* rs = smem; float* rq = smem+8;
    int w = t>>6;
    if ((t&63)==0){ rs[w]=s; rq[w]=q; }
    __syncthreads();
    float S = rs[0]+rs[1]+rs[2]+rs[3];
    float Q = rq[0]+rq[1]+rq[2]+rq[3];
    float mean = S*(1.0f/DM);
    float var  = Q*(1.0f/DM) - mean*mean;
    float rstd = rsqrtf(var + LN_EPS);
    bf16* hr = h + (size_t)bid*DM;
    hr[t]     = (bf16)((v0-mean)*rstd*gamma[t]     + beta[t]);
    hr[t+256] = (bf16)((v1-mean)*rstd*gamma[t+256] + beta[t+256]);
    hr[t+512] = (bf16)((v2-mean)*rstd*gamma[t+512] + beta[t+512]);
  } else {
    int tb = bid - 4096;
    int z = tb/576, rem = tb%576;
    int r0 = (rem/24)*32, c0 = (rem%24)*32;
    int tx = t&31, ty = t>>5;   // (32,8)
    float (*tile)[33] = (float(*)[33])smem;
    const float* src = (z==0)?Wq:(z==1)?Wk:(z==2)?Wv:Wo;
    #pragma unroll
    for (int i=ty;i<32;i+=8) tile[i][tx] = src[(size_t)(r0+i)*DM + c0+tx];
    __syncthreads();
    bf16* dst = (z<3) ? (Wqkvt + (size_t)z*DM*DM) : Wot;
    #pragma unroll
    for (int i=ty;i<32;i+=8) dst[(size_t)(c0+i)*DM + r0+tx] = (bf16)tile[tx][i];
  }
}

// ---------------- GEMM: C = A * Bt^T, BK=32, 3-buffer counted-vmcnt pipeline -
// EPI 0: QKV epilogue (Q cols scaled LOG2E; V -> V^T [b][h][d][n])
// EPI 1: out fp32 = acc + bo[col] + x[row][col]
template<int BM, int BN, int WM, int WN, int EPI>
__global__ __launch_bounds__(256) void gemm_bt(
    const bf16* __restrict__ A, const bf16* __restrict__ Bt, int K,
    bf16* __restrict__ qk, bf16* __restrict__ vt,
    float* __restrict__ out, const float* __restrict__ bo, const float* __restrict__ xres)
{
  constexpr int MF = BM/(WM*16);
  constexpr int NF = BN/(WN*16);
  constexpr int GL = BM/64 + BN/64;   // gloads per wave per stage
  __shared__ bf16 As[3][BM][32];
  __shared__ bf16 Bs[3][BN][32];
  int tid = threadIdx.x, w = tid>>6, la = tid&63;
  int bn = blockIdx.x, bm = blockIdx.y;
  int wm = w / WN, wn = w % WN;
  int g = la>>4, li = la&15;
  int sr = la>>2, sc = (la&3)*8;      // staging: 4 lanes per 32-elem row
  f32x4 acc[MF][NF] = {};
  const int KT = K/32;

  auto stage = [&](int kt, int bb) {
    int k0 = kt*32;
    #pragma unroll
    for (int i=0;i<BM/64;i++){ int r0 = i*64 + w*16;
      gload16(A + ((size_t)(bm*BM + r0 + sr))*K + k0 + sc, &As[bb][r0][0]); }
    #pragma unroll
    for (int i=0;i<BN/64;i++){ int r0 = i*64 + w*16;
      gload16(Bt + ((size_t)(bn*BN + r0 + sr))*K + k0 + sc, &Bs[bb][r0][0]); }
  };

  stage(0,0); stage(1,1);
  asm volatile("s_waitcnt vmcnt(%0)" :: "n"(GL) : "memory");
  __builtin_amdgcn_s_barrier();
  __builtin_amdgcn_sched_barrier(0);

  for (int kt=0; kt<KT; ++kt) {
    int bb = kt%3;
    if (kt+2 < KT) stage(kt+2, (kt+2)%3);
    bf16x8 af[MF], bfr[NF];
    #pragma unroll
    for (int i=0;i<MF;i++) af[i]  = *(const bf16x8*)&As[bb][wm*(BM/WM)+i*16+li][g*8];
    #pragma unroll
    for (int j=0;j<NF;j++) bfr[j] = *(const bf16x8*)&Bs[bb][wn*(BN/WN)+j*16+li][g*8];
    __builtin_amdgcn_s_setprio(1);
    #pragma unroll
    for (int i=0;i<MF;i++)
      #pragma unroll
      for (int j=0;j<NF;j++)
        acc[i][j] = __builtin_amdgcn_mfma_f32_16x16x32_bf16(af[i], bfr[j], acc[i][j], 0,0,0);
    __builtin_amdgcn_s_setprio(0);
    if (kt+1 < KT) {
      if (kt+2 < KT) asm volatile("s_waitcnt vmcnt(%0)" :: "n"(GL) : "memory");
      else           asm volatile("s_waitcnt vmcnt(0)" ::: "memory");
      __builtin_amdgcn_s_barrier();
      __builtin_amdgcn_sched_barrier(0);
    }
  }

  #pragma unroll
  for (int i=0;i<MF;i++){
    int row0 = bm*BM + wm*(BM/WM) + i*16 + g*4;
    #pragma unroll
    for (int j=0;j<NF;j++){
      int col = bn*BN + wn*(BN/WN) + j*16 + li;
      if (EPI==0){
        if (col < 1536) {
          float qs = (col < 768) ? LOG2E : 1.0f;   // uniform per j-tile (768%BN==0)
          #pragma unroll
          for (int r=0;r<4;r++) qk[(size_t)(row0+r)*1536 + col] = (bf16)(acc[i][j][r]*qs);
        } else {
          int cv = col - 1536; int hh = cv>>6, dd = cv&63;
          int b_ = row0>>11,  n0 = row0&2047;
          u16x4 u;
          #pragma unroll
          for (int r=0;r<4;r++){ bf16 bv = (bf16)acc[i][j][r];
            u[r] = __builtin_bit_cast(unsigned short, bv); }
          *reinterpret_cast<u16x4*>(vt + ((size_t)((b_*NH+hh)*HD+dd))*SEQ + n0) = u;
        }
      } else {
        float bb2 = bo[col];
        #pragma unroll
        for (int r=0;r<4;r++){ size_t idx = (size_t)(row0+r)*DM + col;
          out[idx] = acc[i][j][r] + bb2 + xres[idx]; }
      }
    }
  }
}

// ---------------- flash attention: 3-buffer counted-vmcnt + swapped QK ------
// XCD-pinned mapping: id&7 selects XCD, 3 (b,h) pairs per XCD -> K/V (~1.5 MB)
// stays L2-resident (round-5 evidence: FETCH 9.2 MB with this map).
// LDS XOR-swizzle (slot ^= row&7) via pre-swizzled global src; swapped QK
// keeps P lane-local; P->PV-B-frag via cvt_pk + permlane32/16 transposes
// (reg0 word MUST be vdst).
__global__ __launch_bounds__(256) void attn_kernel(
    const bf16* __restrict__ QK, const bf16* __restrict__ Vt, bf16* __restrict__ vals)
{
  __shared__ bf16 Ks[3][64][64];
  __shared__ bf16 Vs[3][64][64];   // V^T tile: [d][kv]
  int tid=threadIdx.x, w=tid>>6, la=tid&63;
  int id = blockIdx.x;
  int xcd = id & 7, idx = id >> 3;       // 768 = 8 * 96, bijective
  int bh  = xcd*3 + (idx>>5);            // 0..23
  int qt  = idx & 31;
  int b = bh/NH, hh = bh%NH;
  int g=la>>4, li=la&15;
  int lr=la>>3;
  int lx=li&7;
  int lcs=((la&7)^lr)*8;           // swizzled source column (elements)
  size_t qrow0=(size_t)b*SEQ + qt*64;

  // Q frags (B-operand: Q[q=li][k]), pre-scaled by LOG2E in GEMM1; registers
  bf16x8 qf[2];
  {
    const bf16* qp = QK + (qrow0 + w*16 + li)*1536 + hh*64;
    qf[0] = *(const bf16x8*)(qp + g*8);
    qf[1] = *(const bf16x8*)(qp + 32 + g*8);
  }

  const bf16* Kbase = QK + (size_t)b*SEQ*1536 + 768 + hh*64;
  const bf16* Vbase = Vt + (size_t)(b*NH+hh)*HD*SEQ;

  auto stage = [&](int tt, int bb) {
    int j0 = tt*64;
    #pragma unroll
    for (int i=0;i<2;i++){ int c=i*4+w;
      gload16(Kbase + (size_t)(j0 + c*8 + lr)*1536 + lcs, &Ks[bb][c*8][0]);
      gload16(Vbase + (size_t)(c*8 + lr)*SEQ + j0 + lcs,  &Vs[bb][c*8][0]); }
  };

  stage(0,0); stage(1,1);
  asm volatile("s_waitcnt vmcnt(4)" ::: "memory");
  __builtin_amdgcn_s_barrier();
  __builtin_amdgcn_sched_barrier(0);

  f32x4 o[4] = {};
  float lp[4] = {0.f,0.f,0.f,0.f};

  for (int t=0;t<32;t++){
    int bb = t%3;
    if (t+2 < 32) stage(t+2, (t+2)%3);
    // S = K Q^T (swapped): lane holds S[kv=nf*16+g*4+r][q=li]
    f32x4 s[4] = {};
    #pragma unroll
    for (int kk=0;kk<2;kk++){
      bf16x8 kf[4];
      #pragma unroll
      for (int nf=0;nf<4;nf++){
        int row = nf*16+li;
        kf[nf] = *(const bf16x8*)((const char*)&Ks[bb][0][0] + row*128 + (((kk*4+g)^lx)<<4));
      }
      __builtin_amdgcn_s_setprio(1);
      #pragma unroll
      for (int nf=0;nf<4;nf++)
        s[nf] = __builtin_amdgcn_mfma_f32_16x16x32_bf16(kf[nf], qf[kk], s[nf], 0,0,0);
      __builtin_amdgcn_s_setprio(0);
    }
    // static-max softmax: p = 2^s, lane-local; shuffle-free
    float p[4][4];
    #pragma unroll
    for (int nf=0;nf<4;nf++){
      #pragma unroll
      for (int r=0;r<4;r++){
        p[nf][r] = __builtin_amdgcn_exp2f(s[nf][r]);
        lp[nf] += p[nf][r];
      }
    }
    // in-register exchange: PV B-frags pa[ks] = P[kv][q=li]
    bf16x8 pa[2];
    #pragma unroll
    for (int ks=0;ks<2;ks++){
      unsigned int c00,c01,c10,c11;
      asm("v_cvt_pk_bf16_f32 %0, %1, %2" : "=v"(c00) : "v"(p[2*ks  ][0]), "v"(p[2*ks  ][1]));
      asm("v_cvt_pk_bf16_f32 %0, %1, %2" : "=v"(c01) : "v"(p[2*ks  ][2]), "v"(p[2*ks  ][3]));
      asm("v_cvt_pk_bf16_f32 %0, %1, %2" : "=v"(c10) : "v"(p[2*ks+1][0]), "v"(p[2*ks+1][1]));
      asm("v_cvt_pk_bf16_f32 %0, %1, %2" : "=v"(c11) : "v"(p[2*ks+1][2]), "v"(p[2*ks+1][3]));
      asm("v_permlane32_swap_b32 %0, %1" : "+v"(c00), "+v"(c10));
      asm("v_permlane32_swap_b32 %0, %1" : "+v"(c01), "+v"(c11));
      asm("v_permlane16_swap_b32 %0, %1" : "+v"(c00), "+v"(c10));
      asm("v_permlane16_swap_b32 %0, %1" : "+v"(c01), "+v"(c11));
      u32x4v cc = {c00, c01, c10, c11};
      pa[ks] = __builtin_bit_cast(bf16x8, cc);
    }
    // PV: O[d][q] += V^T[d][kv] * P[kv][q]
    #pragma unroll
    for (int ks=0;ks<2;ks++){
      bf16x8 vb[4];
      #pragma unroll
      for (int df=0;df<4;df++){
        int row = df*16+li;
        vb[df] = *(const bf16x8*)((const char*)&Vs[bb][0][0] + row*128 + (((ks*4+g)^lx)<<4));
      }
      __builtin_amdgcn_s_setprio(1);
      #pragma unroll
      for (int df=0;df<4;df++)
        o[df] = __builtin_amdgcn_mfma_f32_16x16x32_bf16(vb[df], pa[ks], o[df], 0,0,0);
      __builtin_amdgcn_s_setprio(0);
    }
    if (t+1 < 32) {
      if (t+2 < 32) asm volatile("s_waitcnt vmcnt(4)" ::: "memory");
      else          asm volatile("s_waitcnt vmcnt(0)" ::: "memory");
      __builtin_amdgcn_s_barrier();
      __builtin_amdgcn_sched_barrier(0);
    }
  }
  // lane holds O[d=df*16+g*4+r][q=li]; scale AFTER softmax => O*SCALE/l
  float lsum = lp[0]+lp[1]+lp[2]+lp[3];
  lsum += __shfl_xor(lsum, 16, 64);
  lsum += __shfl_xor(lsum, 32, 64);
  float fac = ATT_SCALE / lsum;
  bf16* vrow = vals + (qrow0 + w*16 + li)*DM + hh*64;
  #pragma unroll
  for (int df=0;df<4;df++){
    u16x4 u;
    #pragma unroll
    for (int r=0;r<4;r++){
      bf16 bv = (bf16)(o[df][r] * fac);
      u[r] = __builtin_bit_cast(unsigned short, bv);
    }
    *reinterpret_cast<u16x4*>(vrow + df*16 + g*4) = u;
  }
}

// ---------------- launch -----------------------------------------------------
extern "C" void kernel_launch(void* const* d_in, const int* in_sizes, int n_in,
                              void* d_out, int out_size, void* d_ws, size_t ws_size,
                              hipStream_t stream)
{
  const float* x     = (const float*)d_in[0];
  const float* Wq    = (const float*)d_in[1];
  const float* Wk    = (const float*)d_in[2];
  const float* Wv    = (const float*)d_in[3];
  const float* Wo    = (const float*)d_in[4];
  const float* bo    = (const float*)d_in[5];
  const float* gamma = (const float*)d_in[6];
  const float* beta  = (const float*)d_in[7];
  float* out = (float*)d_out;
  char* ws = (char*)d_ws;

  bf16* h     = (bf16*)(ws + 0);          // 4096*768*2    = 6291456
  bf16* vals  = (bf16*)(ws + 0);          // alias of h (h dead after GEMM1)
  bf16* Wqkvt = (bf16*)(ws + 6291456);    // 2304*768*2    = 3538944
  bf16* Wot   = (bf16*)(ws + 9830400);    // 768*768*2     = 1179648
  bf16* QKb   = (bf16*)(ws + 11010048);   // 4096*1536*2   = 12582912
  bf16* Vt    = (bf16*)(ws + 23592960);   // 24*64*2048*2  = 6291456
  (void)ws_size; (void)in_sizes; (void)n_in; (void)out_size;

  prep_kernel<<<dim3(6400), dim3(256), 0, stream>>>(
      x, gamma, beta, h, Wq, Wk, Wv, Wo, Wqkvt, Wot);
  gemm_bt<128,128,2,2,0><<<dim3(18,32), dim3(256), 0, stream>>>(
      h, Wqkvt, DM, QKb, Vt, nullptr, nullptr, nullptr);
  attn_kernel<<<dim3(768), dim3(256), 0, stream>>>(QKb, Vt, vals);
  gemm_bt<64,64,2,2,1><<<dim3(12,64), dim3(256), 0, stream>>>(
      vals, Wot, DM, nullptr, nullptr, out, bo, x);
}